// Round 1
// baseline (948.445 us; speedup 1.0000x reference)
//
#include <hip/hip_runtime.h>
#include <math.h>

#ifndef M_PI
#define M_PI 3.14159265358979323846
#endif

#define NJ    64      // 2*B_IN
#define NSPEC 256     // B_OUT^2
#define NGRID 24
#define NB    16      // batch
#define FIN   64
#define FOUT  64
#define NOUTD 32      // 2*B_OUT
#define NLMN  5456    // sum (2l+1)^2, l<16

__device__ __forceinline__ int loff(int l){ return (4*l*l*l - l)/3; }

__device__ __forceinline__ void lm_from_s(int s, int& l, int& m){
  int ll = 0;
  while ((ll+1)*(ll+1) <= s) ll++;
  l = ll; m = s - ll*ll - ll;
}

// Wigner small-d, quantum norm, CS phase. double precision.
__device__ double wigner_d_dev(int l, int mp, int m, double beta, const double* LF){
  double c = cos(0.5*beta), s = sin(0.5*beta);
  double pref = 0.5*(LF[l+mp] + LF[l-mp] + LF[l+m] + LF[l-m]);
  int lo = max(0, m-mp), hi = min(l+m, l-mp);
  double v = 0.0;
  for (int k = lo; k <= hi; ++k){
    double lg = pref - (LF[l+m-k] + LF[k] + LF[mp-m+k] + LF[l-mp-k]);
    double t = exp(lg) * pow(c, (double)(2*l + m - mp - 2*k)) * pow(s, (double)(mp - m + 2*k));
    v += ((mp - m + k) & 1) ? -t : t;
  }
  return v;
}

// ---- constants ----
__global__ void k0_consts(double* LF, double* wq){
  int t = threadIdx.x;
  if (t == 0){
    LF[0] = 0.0;
    double acc = 0.0;
    for (int i = 1; i < 70; ++i){ acc += log((double)i); LF[i] = acc; }
  }
  if (t < NJ){
    double b = 32.0;  // B_IN
    double sum = 0.0;
    for (int k = 0; k < 32; ++k)
      sum += sin((2.0*t+1.0)*(2.0*k+1.0)*M_PI/(4.0*b)) / (2.0*k+1.0);
    double a = (2.0/b) * sin(M_PI*(2.0*t+1.0)/(4.0*b)) * sum;
    wq[t] = a * M_PI / b;
  }
}

// wig[s][j] = w(beta_j) * d^l_{m,0}(beta_j)
__global__ void k1a_wig(const double* LF, const double* wq, float* wig){
  int s = blockIdx.x, j = threadIdx.x;
  int l, m; lm_from_s(s, l, m);
  double beta = (j + 0.5) * M_PI / (double)NJ;
  wig[s*NJ + j] = (float)(wq[j] * wigner_d_dev(l, m, 0, beta, LF));
}

// Fc[s][a] = conj(F[a][s]) = sqrt((2l+1)/4pi) * e^{+i m alpha} * d^l_{m,0}(beta)
__global__ void k1b_fc(const double* LF, float2* Fc){
  int gid = blockIdx.x * blockDim.x + threadIdx.x;
  if (gid >= NSPEC * NGRID) return;
  int s = gid / NGRID, a = gid % NGRID;
  int l, m; lm_from_s(s, l, m);
  int bidx = a / 8, aidx = a % 8;
  double beta  = (bidx + 1) * (M_PI / 8.0) / 3.0;
  double alpha = aidx * (M_PI / 4.0);
  double d  = wigner_d_dev(l, m, 0, beta, LF);
  double sq = sqrt((2.0*l + 1.0) / (4.0 * M_PI));
  Fc[s*NGRID + a] = make_float2((float)(sq*d*cos(m*alpha)), (float)(sq*d*sin(m*alpha)));
}

// D[j][lmn] = (2l+1) * d^l_{mp,mm}(beta_out_j)
__global__ void k1c_D(const double* LF, float* D){
  int gid = blockIdx.x * blockDim.x + threadIdx.x;
  if (gid >= NOUTD * NLMN) return;
  int j = gid / NLMN, r = gid % NLMN;
  int l = 0;
  while (loff(l+1) <= r) l++;
  int t = r - loff(l), nm = 2*l + 1;
  int mp = t / nm - l, mm = t % nm - l;
  double beta = (j + 0.5) * M_PI / (double)NOUTD;
  D[gid] = (float)((2*l + 1) * wigner_d_dev(l, mp, mm, beta, LF));
}

// ---- xfreq[mu][j][b][i] = sum_a x[b,i,j,a] e^{-2pi i a mu/64}, mu=0..15 ----
__global__ __launch_bounds__(256) void k2_xfreq(const float* __restrict__ x, float2* __restrict__ xf){
  __shared__ float  xt[64*64];
  __shared__ float2 tw[64];
  int bid = blockIdx.x;
  int b = bid >> 6, i = bid & 63;
  const float* xp = x + (size_t)(b*64 + i) * 4096;
  for (int t = threadIdx.x; t < 4096; t += 256) xt[t] = xp[t];
  if (threadIdx.x < 64){
    float sv, cv;
    sincosf(-2.0f * (float)M_PI * threadIdx.x / 64.0f, &sv, &cv);
    tw[threadIdx.x] = make_float2(cv, sv);
  }
  __syncthreads();
  for (int t = threadIdx.x; t < 1024; t += 256){
    int mu = t >> 6, j = t & 63;
    float2 acc = make_float2(0.f, 0.f);
    const float* row = xt + j*64;
    for (int a = 0; a < 64; ++a){
      float2 w = tw[(a*mu) & 63];
      acc.x += row[a]*w.x;
      acc.y += row[a]*w.y;
    }
    xf[(size_t)((mu*64 + j)*16 + b)*64 + i] = acc;
  }
}

// ---- xhat[s][b][i] = sum_j wig[s][j] * xf(b,i,j, m mod 64) ----
__global__ __launch_bounds__(64) void k3_xhat(const float2* __restrict__ xf, const float* __restrict__ wig,
                                              float2* __restrict__ xhat){
  int blk = blockIdx.x;
  int s = blk >> 4, b = blk & 15, i = threadIdx.x;
  int l, m; lm_from_s(s, l, m);
  int mu = (m < 0) ? -m : m;   // xf[64-|m|] = conj(xf[|m|]) for real input
  float2 acc = make_float2(0.f, 0.f);
  for (int j = 0; j < NJ; ++j){
    float w = wig[s*NJ + j];
    float2 v = xf[(size_t)((mu*64 + j)*16 + b)*64 + i];
    acc.x += w*v.x;
    acc.y += w*v.y;
  }
  if (m < 0) acc.y = -acc.y;
  xhat[(size_t)(s*16 + b)*64 + i] = acc;
}

// ---- yhc[s][o][i] = conj(yhat) = sum_a kern[i,o,a] * Fc[s][a] ----
__global__ __launch_bounds__(256) void k4_yhc(const float* __restrict__ kern, const float2* __restrict__ Fc,
                                              float2* __restrict__ yhc){
  __shared__ float2 fc[NGRID];
  int s = blockIdx.x;
  if (threadIdx.x < NGRID) fc[threadIdx.x] = Fc[s*NGRID + threadIdx.x];
  __syncthreads();
  for (int p = threadIdx.x; p < FOUT*FIN; p += 256){
    int o = p >> 6, i = p & 63;
    const float* kp = kern + (size_t)(i*FOUT + o)*NGRID;
    float2 acc = make_float2(0.f, 0.f);
    for (int a = 0; a < NGRID; ++a){
      float k = kp[a];
      acc.x += k * fc[a].x;
      acc.y += k * fc[a].y;
    }
    yhc[(size_t)(s*FOUT + o)*FIN + i] = acc;
  }
}

// ---- Z[bloc][o][lmn] = sum_i xhat[l,m][b][i] * yhc[l,n][o][i] ----
__global__ __launch_bounds__(256) void k5_z(const float2* __restrict__ xhat, const float2* __restrict__ yhc,
                                            float2* __restrict__ Z, int b0){
  __shared__ float Xr[31*65], Xi[31*65], Yr[31*65], Yi[31*65];
  int bloc = blockIdx.x >> 6, o = blockIdx.x & 63;
  int b = b0 + bloc;
  float2* zout = Z + (size_t)(bloc*64 + o) * NLMN;
  for (int l = 0; l < 16; ++l){
    int nm = 2*l + 1, s0 = l*l;
    for (int t = threadIdx.x; t < nm*64; t += 256){
      int r = t >> 6, i = t & 63;
      float2 xv = xhat[(size_t)((s0 + r)*16 + b)*64 + i];
      Xr[r*65 + i] = xv.x; Xi[r*65 + i] = xv.y;
      float2 yv = yhc[(size_t)((s0 + r)*64 + o)*64 + i];
      Yr[r*65 + i] = yv.x; Yi[r*65 + i] = yv.y;
    }
    __syncthreads();
    int base = loff(l);
    for (int t = threadIdx.x; t < nm*nm; t += 256){
      int mr = t / nm, nr = t % nm;
      const float* xr = Xr + mr*65; const float* xi = Xi + mr*65;
      const float* yr = Yr + nr*65; const float* yi = Yi + nr*65;
      float ar = 0.f, ai = 0.f;
      for (int i = 0; i < 64; ++i){
        float a = xr[i], bb = xi[i], c = yr[i], d = yi[i];
        ar += a*c - bb*d;
        ai += a*d + bb*c;
      }
      zout[base + t] = make_float2(ar, ai);
    }
    __syncthreads();
  }
}

// ---- per (b,o,j): W[m][n] = sum_l Z*D ; out[a][g] = Re sum_{m,n} W e^{2pi i(ma+ng)/32} ----
__global__ __launch_bounds__(256) void k6_out(const float2* __restrict__ Z, const float* __restrict__ D,
                                              const float* __restrict__ bias, float* __restrict__ out, int b0){
  __shared__ float2 W[31*31];
  __shared__ float2 T[31*32];
  __shared__ float2 tw[32];
  int bid = blockIdx.x;
  int j = bid & 31, o = (bid >> 5) & 63, bloc = bid >> 11;
  int b = b0 + bloc;
  const float2* zp = Z + (size_t)(bloc*64 + o) * NLMN;
  const float*  dp = D + (size_t)j * NLMN;
  if (threadIdx.x < 32){
    float sv, cv;
    sincosf(2.0f * (float)M_PI * threadIdx.x / 32.0f, &sv, &cv);
    tw[threadIdx.x] = make_float2(cv, sv);   // e^{+2pi i k/32}
  }
  for (int t = threadIdx.x; t < 31*31; t += 256) W[t] = make_float2(0.f, 0.f);
  __syncthreads();
  for (int l = 0; l < 16; ++l){
    int nm = 2*l + 1, base = loff(l);
    for (int t = threadIdx.x; t < nm*nm; t += 256){
      int mr = t / nm, nr = t % nm;
      float2 z = zp[base + t];
      float  d = dp[base + t];
      int slot = (mr - l + 15)*31 + (nr - l + 15);
      W[slot].x += z.x * d;
      W[slot].y += z.y * d;
    }
    __syncthreads();
  }
  // stage 1: T[sm][g] = sum_sn W[sm][sn] * e^{2pi i (sn-15) g / 32}
  for (int t = threadIdx.x; t < 31*32; t += 256){
    int sm = t >> 5, g = t & 31;
    float tr = 0.f, ti = 0.f;
    for (int sn = 0; sn < 31; ++sn){
      float2 w = W[sm*31 + sn];
      float2 e = tw[((sn - 15) * g) & 31];
      tr += w.x*e.x - w.y*e.y;
      ti += w.x*e.y + w.y*e.x;
    }
    T[sm*32 + g] = make_float2(tr, ti);
  }
  __syncthreads();
  float bo = bias[o];
  float* op = out + (size_t)((b*64 + o)*32 + j) * 1024;
  for (int t = threadIdx.x; t < 1024; t += 256){
    int a = t >> 5, g = t & 31;
    float acc = 0.f;
    for (int sm = 0; sm < 31; ++sm){
      float2 tv = T[sm*32 + g];
      float2 e  = tw[((sm - 15) * a) & 31];
      acc += tv.x*e.x - tv.y*e.y;
    }
    op[t] = acc + bo;
  }
}

extern "C" void kernel_launch(void* const* d_in, const int* in_sizes, int n_in,
                              void* d_out, int out_size, void* d_ws, size_t ws_size,
                              hipStream_t stream){
  const float* x    = (const float*)d_in[0];
  const float* kern = (const float*)d_in[1];
  const float* bias = (const float*)d_in[2];
  float* out = (float*)d_out;

  char* ws = (char*)d_ws;
  size_t off = 0;
  auto alloc = [&](size_t bytes) -> char* {
    char* p = ws + off;
    off = (off + bytes + 511) & ~(size_t)511;
    return p;
  };
  double* LF   = (double*)alloc(70 * 8);
  double* wq   = (double*)alloc(64 * 8);
  float*  wig  = (float* )alloc((size_t)NSPEC * NJ * 4);
  float2* Fc   = (float2*)alloc((size_t)NSPEC * NGRID * 8);
  float*  D    = (float* )alloc((size_t)NOUTD * NLMN * 4);
  float2* xf   = (float2*)alloc((size_t)16 * 64 * 16 * 64 * 8);   // [mu][j][b][i]
  float2* xhat = (float2*)alloc((size_t)NSPEC * NB * FIN * 8);
  float2* yhc  = (float2*)alloc((size_t)NSPEC * FOUT * FIN * 8);
  size_t fixed = off;

  // choose batch chunk for Z to fit in workspace
  size_t zbytes_per_b = (size_t)FOUT * NLMN * 8;   // 2.79 MB per batch element
  int chunk = NB;
  while (chunk > 1 && fixed + (size_t)chunk * zbytes_per_b > ws_size) chunk >>= 1;
  float2* Z = (float2*)alloc((size_t)chunk * zbytes_per_b);

  hipLaunchKernelGGL(k0_consts, dim3(1), dim3(256), 0, stream, LF, wq);
  hipLaunchKernelGGL(k1a_wig,  dim3(NSPEC), dim3(NJ), 0, stream, LF, wq, wig);
  hipLaunchKernelGGL(k1b_fc,   dim3((NSPEC*NGRID + 255)/256), dim3(256), 0, stream, LF, Fc);
  hipLaunchKernelGGL(k1c_D,    dim3((NOUTD*NLMN + 255)/256), dim3(256), 0, stream, LF, D);
  hipLaunchKernelGGL(k2_xfreq, dim3(NB*FIN), dim3(256), 0, stream, x, xf);
  hipLaunchKernelGGL(k3_xhat,  dim3(NSPEC*NB), dim3(64), 0, stream, xf, wig, xhat);
  hipLaunchKernelGGL(k4_yhc,   dim3(NSPEC), dim3(256), 0, stream, kern, Fc, yhc);

  for (int b0 = 0; b0 < NB; b0 += chunk){
    hipLaunchKernelGGL(k5_z,   dim3(chunk*FOUT), dim3(256), 0, stream, xhat, yhc, Z, b0);
    hipLaunchKernelGGL(k6_out, dim3(chunk*FOUT*NOUTD), dim3(256), 0, stream, Z, D, bias, out, b0);
  }
}

// Round 2
// 459.931 us; speedup vs baseline: 2.0621x; 2.0621x over previous
//
#include <hip/hip_runtime.h>
#include <math.h>

#ifndef M_PI
#define M_PI 3.14159265358979323846
#endif

#define NJ    64      // 2*B_IN
#define NGRID 24
#define NB    16      // batch
#define FIN   64
#define FOUT  64
#define NOUTD 32      // 2*B_OUT
#define NHALF 2856    // sum_{l<16} (l+1)(2l+1)  (m>=0 half)
#define NH2   136     // sum_{l<16} (l+1)

__device__ __forceinline__ int hoff(int l){ return l*(l+1)*(4*l-1)/6; }
__device__ __forceinline__ int h2off(int l){ return l*(l+1)/2; }

__device__ __forceinline__ void lm_from_s(int s, int& l, int& m){
  int ll = 0;
  while ((ll+1)*(ll+1) <= s) ll++;
  l = ll; m = s - ll*ll - ll;
}

// Wigner small-d, quantum norm, CS phase. double precision.
__device__ double wigner_d_dev(int l, int mp, int m, double beta, const double* LF){
  double c = cos(0.5*beta), s = sin(0.5*beta);
  double pref = 0.5*(LF[l+mp] + LF[l-mp] + LF[l+m] + LF[l-m]);
  int lo = max(0, m-mp), hi = min(l+m, l-mp);
  double v = 0.0;
  for (int k = lo; k <= hi; ++k){
    double lg = pref - (LF[l+m-k] + LF[k] + LF[mp-m+k] + LF[l-mp-k]);
    double t = exp(lg) * pow(c, (double)(2*l + m - mp - 2*k)) * pow(s, (double)(mp - m + 2*k));
    v += ((mp - m + k) & 1) ? -t : t;
  }
  return v;
}

// ---- constants ----
__global__ void k0_consts(double* LF, double* wq){
  int t = threadIdx.x;
  if (t == 0){
    LF[0] = 0.0;
    double acc = 0.0;
    for (int i = 1; i < 70; ++i){ acc += log((double)i); LF[i] = acc; }
  }
  if (t < NJ){
    double b = 32.0;  // B_IN
    double sum = 0.0;
    for (int k = 0; k < 32; ++k)
      sum += sin((2.0*t+1.0)*(2.0*k+1.0)*M_PI/(4.0*b)) / (2.0*k+1.0);
    double a = (2.0/b) * sin(M_PI*(2.0*t+1.0)/(4.0*b)) * sum;
    wq[t] = a * M_PI / b;
  }
}

// wig[s][j] = w(beta_j) * d^l_{m,0}(beta_j)   (full s range; only m>=0 rows get used)
__global__ void k1a_wig(const double* LF, const double* wq, float* wig){
  int s = blockIdx.x, j = threadIdx.x;
  int l, m; lm_from_s(s, l, m);
  double beta = (j + 0.5) * M_PI / (double)NJ;
  wig[s*NJ + j] = (float)(wq[j] * wigner_d_dev(l, m, 0, beta, LF));
}

// Fc[s][a] = conj(F[a][s]) = sqrt((2l+1)/4pi) * e^{+i m alpha} * d^l_{m,0}(beta)
__global__ void k1b_fc(const double* LF, float2* Fc){
  int gid = blockIdx.x * blockDim.x + threadIdx.x;
  if (gid >= 256 * NGRID) return;
  int s = gid / NGRID, a = gid % NGRID;
  int l, m; lm_from_s(s, l, m);
  int bidx = a / 8, aidx = a % 8;
  double beta  = (bidx + 1) * (M_PI / 8.0) / 3.0;
  double alpha = aidx * (M_PI / 4.0);
  double d  = wigner_d_dev(l, m, 0, beta, LF);
  double sq = sqrt((2.0*l + 1.0) / (4.0 * M_PI));
  Fc[s*NGRID + a] = make_float2((float)(sq*d*cos(m*alpha)), (float)(sq*d*sin(m*alpha)));
}

// D[j][hoff(l)+m*(2l+1)+n+l] = (2l+1) * d^l_{m,n}(beta_out_j), m>=0
__global__ void k1c_D(const double* LF, float* D){
  int gid = blockIdx.x * blockDim.x + threadIdx.x;
  if (gid >= NOUTD * NHALF) return;
  int j = gid / NHALF, r = gid % NHALF;
  int l = 0;
  while (hoff(l+1) <= r) l++;
  int t = r - hoff(l), nm = 2*l + 1;
  int m = t / nm, n = t % nm - l;
  double beta = (j + 0.5) * M_PI / (double)NOUTD;
  D[gid] = (float)((2*l + 1) * wigner_d_dev(l, m, n, beta, LF));
}

// kt[o][a][i] = kern[i][o][a]   (one-time transpose so k4 reads coalesced)
__global__ __launch_bounds__(256) void k1e_kt(const float* __restrict__ kern, float* __restrict__ kt){
  int o = blockIdx.x;
  for (int t = threadIdx.x; t < NGRID*64; t += 256){
    int a = t >> 6, i = t & 63;
    kt[(o*NGRID + a)*64 + i] = kern[(i*64 + o)*NGRID + a];
  }
}

// ---- xfreq[mu][j][b][i] = sum_a x[b,i,j,a] e^{-2pi i a mu/64}, mu=0..15 ----
__global__ __launch_bounds__(256) void k2_xfreq(const float* __restrict__ x, float2* __restrict__ xf){
  __shared__ float xt[64*65];
  int bid = blockIdx.x;
  int b = bid >> 6, i = bid & 63;
  const float* xp = x + (size_t)(b*64 + i) * 4096;
  for (int t = threadIdx.x; t < 4096; t += 256) xt[(t >> 6)*65 + (t & 63)] = xp[t];
  __syncthreads();
  for (int t = threadIdx.x; t < 1024; t += 256){
    int mu = t >> 6, j = t & 63;
    float sv, cv;
    sincosf(-2.0f * (float)M_PI * (float)mu / 64.0f, &sv, &cv);
    float cr = 1.f, ci = 0.f;           // rotation e^{-2pi i a mu/64}
    float ar = 0.f, ai = 0.f;
    const float* row = xt + j*65;
    #pragma unroll
    for (int a = 0; a < 64; ++a){
      float v = row[a];
      ar = fmaf(v, cr, ar);
      ai = fmaf(v, ci, ai);
      float nc = cr*cv - ci*sv, ns = cr*sv + ci*cv;
      cr = nc; ci = ns;
    }
    xf[(size_t)((mu*64 + j)*16 + b)*64 + i] = make_float2(ar, ai);
  }
}

// ---- xhat[h][b][i] = sum_j wig[s][j] * xf(b,i,j,m), h = l(l+1)/2 + m, m>=0 ----
__global__ __launch_bounds__(64) void k3_xhat(const float2* __restrict__ xf, const float* __restrict__ wig,
                                              float2* __restrict__ xhat){
  int blk = blockIdx.x;
  int h = blk >> 4, b = blk & 15, i = threadIdx.x;
  int l = 0;
  while (h2off(l+1) <= h) l++;
  int m = h - h2off(l);
  int s = l*l + l + m;
  float2 acc = make_float2(0.f, 0.f);
  for (int j = 0; j < NJ; ++j){
    float w = wig[s*NJ + j];
    float2 v = xf[(size_t)((m*64 + j)*16 + b)*64 + i];
    acc.x = fmaf(w, v.x, acc.x);
    acc.y = fmaf(w, v.y, acc.y);
  }
  xhat[(size_t)(h*16 + b)*64 + i] = acc;
}

// ---- yhc[s][o][i] = sum_a kt[o][a][i] * Fc[s][a]  (full s range; conj(yhat)) ----
__global__ __launch_bounds__(256) void k4_yhc(const float* __restrict__ kt, const float2* __restrict__ Fc,
                                              float2* __restrict__ yhc){
  __shared__ float2 fc[NGRID];
  int s = blockIdx.x;
  if (threadIdx.x < NGRID) fc[threadIdx.x] = Fc[s*NGRID + threadIdx.x];
  __syncthreads();
  for (int p = threadIdx.x; p < FOUT*FIN; p += 256){
    int o = p >> 6, i = p & 63;
    float2 acc = make_float2(0.f, 0.f);
    for (int a = 0; a < NGRID; ++a){
      float k = kt[(o*NGRID + a)*64 + i];
      acc.x = fmaf(k, fc[a].x, acc.x);
      acc.y = fmaf(k, fc[a].y, acc.y);
    }
    yhc[(size_t)(s*FOUT + o)*FIN + i] = acc;
  }
}

// ---- Z[bloc][o][half-lmn] = sum_i xhat[l,m][b][i] * yhc[l,n][o][i],  m>=0 ----
__global__ __launch_bounds__(256) void k5_z(const float2* __restrict__ xhat, const float2* __restrict__ yhc,
                                            float2* __restrict__ Z, int b0){
  __shared__ float2 Xs[16*65];
  __shared__ float2 Ys[31*65];
  int bloc = blockIdx.x >> 6, o = blockIdx.x & 63;
  int b = b0 + bloc;
  float2* zout = Z + (size_t)(bloc*64 + o) * NHALF;
  int rt = threadIdx.x >> 4, ct = threadIdx.x & 15;   // m = rt, n0 = 2*ct
  for (int l = 0; l < 16; ++l){
    int rx = l + 1, ry = 2*l + 1;
    for (int t = threadIdx.x; t < rx*64; t += 256){
      int r = t >> 6, i = t & 63;
      Xs[r*65 + i] = xhat[(size_t)((h2off(l) + r)*16 + b)*64 + i];
    }
    for (int t = threadIdx.x; t < ry*64; t += 256){
      int r = t >> 6, i = t & 63;
      Ys[r*65 + i] = yhc[(size_t)((l*l + r)*FOUT + o)*FIN + i];
    }
    __syncthreads();
    int n0 = 2*ct;
    bool act = (rt <= l) && (n0 <= 2*l);
    if (act){
      int n1 = min(n0 + 1, 2*l);
      float z0r = 0.f, z0i = 0.f, z1r = 0.f, z1i = 0.f;
      const float2* xr = Xs + rt*65;
      const float2* y0 = Ys + n0*65;
      const float2* y1 = Ys + n1*65;
      #pragma unroll 8
      for (int i = 0; i < 64; ++i){
        float2 xv = xr[i];
        float2 a0 = y0[i], a1 = y1[i];
        z0r += xv.x*a0.x - xv.y*a0.y;  z0i += xv.x*a0.y + xv.y*a0.x;
        z1r += xv.x*a1.x - xv.y*a1.y;  z1i += xv.x*a1.y + xv.y*a1.x;
      }
      int base = hoff(l) + rt*(2*l+1);
      zout[base + n0] = make_float2(z0r, z0i);
      if (n0 + 1 <= 2*l) zout[base + n0 + 1] = make_float2(z1r, z1i);
    }
    __syncthreads();
  }
}

// ---- per (b,o,j): W[m>=0][n] -> A/B[m][g] -> out[a][g] (Hermitian-halved IFFT2) ----
__global__ __launch_bounds__(256) void k6_out(const float2* __restrict__ Z, const float* __restrict__ D,
                                              const float* __restrict__ bias, float* __restrict__ out, int b0){
  __shared__ float2 tw32[32];
  __shared__ float2 Wl[16*32];   // [m][nn], nn=0..30 used
  __shared__ float2 AB[16*32];   // [m][g] = (w*A, w*B)
  __shared__ float  o32[1024];   // [a][g]
  int bid = blockIdx.x;
  int j = bid & 31, o = (bid >> 5) & 63, bloc = bid >> 11;
  int tid = threadIdx.x;
  const float2* zp = Z + (size_t)(bloc*64 + o) * NHALF;
  const float*  dp = D + (size_t)j * NHALF;
  if (tid < 32){
    float sv, cv;
    sincosf(2.0f * (float)M_PI * tid / 32.0f, &sv, &cv);
    tw32[tid] = make_float2(cv, sv);   // e^{+2pi i k/32}
  }
  // W-build: owner-computes, incremental index (no div/mod, no LDS RMW)
  #pragma unroll
  for (int pp = 0; pp < 2; ++pp){
    int p = tid + pp*256;
    int m = p >> 5, nn = p & 31;
    float2 acc = make_float2(0.f, 0.f);
    if (nn < 31){
      int n  = nn - 15;
      int na = n < 0 ? -n : n;
      int lmin = m > na ? m : na;
      int idx = hoff(lmin) + m*(2*lmin + 1) + n + lmin;
      for (int l = lmin; l < 16; ++l){
        float2 z = zp[idx];
        float  d = dp[idx];
        acc.x = fmaf(z.x, d, acc.x);
        acc.y = fmaf(z.y, d, acc.y);
        idx += (l + 1)*(2*l + 1) + 2*m + 1;
      }
    }
    Wl[p] = acc;
  }
  __syncthreads();
  // phase 1: A[m][g] + iB[m][g] = sum_n W[m][n] e^{2pi i n g/32}, m = m0, m0+8
  {
    int g = tid & 31, m0 = tid >> 5;
    float2 st = tw32[(17*g) & 31];   // e^{-i 15 g w}, w = 2pi/32
    float2 sp = tw32[g];             // step e^{+i g w}
    float A0 = 0.f, B0 = 0.f, A1 = 0.f, B1 = 0.f;
    const float2* w0p = Wl + m0*32;
    const float2* w1p = Wl + (m0 + 8)*32;
    #pragma unroll
    for (int nn = 0; nn < 31; ++nn){
      float2 w0 = w0p[nn], w1 = w1p[nn];
      A0 = fmaf(w0.x, st.x, A0); A0 = fmaf(-w0.y, st.y, A0);
      B0 = fmaf(w0.x, st.y, B0); B0 = fmaf( w0.y, st.x, B0);
      A1 = fmaf(w1.x, st.x, A1); A1 = fmaf(-w1.y, st.y, A1);
      B1 = fmaf(w1.x, st.y, B1); B1 = fmaf( w1.y, st.x, B1);
      float nc = st.x*sp.x - st.y*sp.y;
      float ns = st.x*sp.y + st.y*sp.x;
      st.x = nc; st.y = ns;
    }
    __syncthreads();
    float w0s = (m0 == 0) ? 1.f : 2.f;
    AB[m0*32 + g]       = make_float2(w0s*A0, w0s*B0);
    AB[(m0 + 8)*32 + g] = make_float2(2.f*A1, 2.f*B1);
  }
  __syncthreads();
  // phase 2: out[a][g] = sum_m (A~ cos(m a w) - B~ sin(m a w));  a+16 -> (-1)^m
  {
    int g0 = tid & 15, a0 = tid >> 4;
    float2 ct = make_float2(1.f, 0.f);
    float2 cs = tw32[a0];
    float o00 = 0.f, o01 = 0.f, o10 = 0.f, o11 = 0.f;
    #pragma unroll
    for (int m = 0; m < 16; ++m){
      float2 ab0 = AB[m*32 + g0];
      float2 ab1 = AB[m*32 + g0 + 16];
      float t0 = ab0.x*ct.x - ab0.y*ct.y;
      float t1 = ab1.x*ct.x - ab1.y*ct.y;
      o00 += t0; o01 += t1;
      if (m & 1){ o10 -= t0; o11 -= t1; } else { o10 += t0; o11 += t1; }
      float nc = ct.x*cs.x - ct.y*cs.y;
      float ns = ct.x*cs.y + ct.y*cs.x;
      ct.x = nc; ct.y = ns;
    }
    o32[a0*32 + g0]           = o00;
    o32[a0*32 + g0 + 16]      = o01;
    o32[(a0+16)*32 + g0]      = o10;
    o32[(a0+16)*32 + g0 + 16] = o11;
  }
  __syncthreads();
  float bo = bias[o];
  float4* op = (float4*)(out + (size_t)(((b0 + bloc)*64 + o)*32 + j) * 1024);
  float4 v = ((float4*)o32)[tid];
  v.x += bo; v.y += bo; v.z += bo; v.w += bo;
  op[tid] = v;
}

extern "C" void kernel_launch(void* const* d_in, const int* in_sizes, int n_in,
                              void* d_out, int out_size, void* d_ws, size_t ws_size,
                              hipStream_t stream){
  const float* x    = (const float*)d_in[0];
  const float* kern = (const float*)d_in[1];
  const float* bias = (const float*)d_in[2];
  float* out = (float*)d_out;

  char* ws = (char*)d_ws;
  size_t off = 0;
  auto alloc = [&](size_t bytes) -> char* {
    char* p = ws + off;
    off = (off + bytes + 511) & ~(size_t)511;
    return p;
  };
  double* LF   = (double*)alloc(70 * 8);
  double* wq   = (double*)alloc(64 * 8);
  float*  wig  = (float* )alloc((size_t)256 * NJ * 4);
  float2* Fc   = (float2*)alloc((size_t)256 * NGRID * 8);
  float*  D    = (float* )alloc((size_t)NOUTD * NHALF * 4);
  float*  kt   = (float* )alloc((size_t)FOUT * NGRID * 64 * 4);
  float2* xf   = (float2*)alloc((size_t)16 * 64 * 16 * 64 * 8);   // [mu][j][b][i]
  float2* xhat = (float2*)alloc((size_t)NH2 * NB * FIN * 8);
  float2* yhc  = (float2*)alloc((size_t)256 * FOUT * FIN * 8);
  size_t fixed = off;

  size_t zbytes_per_b = (size_t)FOUT * NHALF * 8;   // 1.46 MB per batch element
  int chunk = NB;
  while (chunk > 1 && fixed + (size_t)chunk * zbytes_per_b > ws_size) chunk >>= 1;
  float2* Z = (float2*)alloc((size_t)chunk * zbytes_per_b);

  hipLaunchKernelGGL(k0_consts, dim3(1), dim3(256), 0, stream, LF, wq);
  hipLaunchKernelGGL(k1a_wig,  dim3(256), dim3(NJ), 0, stream, LF, wq, wig);
  hipLaunchKernelGGL(k1b_fc,   dim3((256*NGRID + 255)/256), dim3(256), 0, stream, LF, Fc);
  hipLaunchKernelGGL(k1c_D,    dim3((NOUTD*NHALF + 255)/256), dim3(256), 0, stream, LF, D);
  hipLaunchKernelGGL(k1e_kt,   dim3(FOUT), dim3(256), 0, stream, kern, kt);
  hipLaunchKernelGGL(k2_xfreq, dim3(NB*FIN), dim3(256), 0, stream, x, xf);
  hipLaunchKernelGGL(k3_xhat,  dim3(NH2*NB), dim3(64), 0, stream, xf, wig, xhat);
  hipLaunchKernelGGL(k4_yhc,   dim3(256), dim3(256), 0, stream, kt, Fc, yhc);

  for (int b0 = 0; b0 < NB; b0 += chunk){
    hipLaunchKernelGGL(k5_z,   dim3(chunk*FOUT), dim3(256), 0, stream, xhat, yhc, Z, b0);
    hipLaunchKernelGGL(k6_out, dim3(chunk*FOUT*NOUTD), dim3(256), 0, stream, Z, D, bias, out, b0);
  }
}

// Round 4
// 392.306 us; speedup vs baseline: 2.4176x; 1.1724x over previous
//
#include <hip/hip_runtime.h>
#include <math.h>

#ifndef M_PI
#define M_PI 3.14159265358979323846
#endif

#define NJ    64      // 2*B_IN
#define NGRID 24
#define NB    16      // batch
#define FIN   64
#define FOUT  64
#define NOUTD 32      // 2*B_OUT
#define NHALF 2856    // sum_{l<16} (l+1)(2l+1)  (m>=0 half)
#define NH2   136     // sum_{l<16} (l+1)

typedef __attribute__((ext_vector_type(8))) short short8;
typedef __attribute__((ext_vector_type(4))) float f32x4;

__device__ __forceinline__ int hoff(int l){ return l*(l+1)*(4*l-1)/6; }
__device__ __forceinline__ int h2off(int l){ return l*(l+1)/2; }

__device__ __forceinline__ void lm_from_s(int s, int& l, int& m){
  int ll = 0;
  while ((ll+1)*(ll+1) <= s) ll++;
  l = ll; m = s - ll*ll - ll;
}

__device__ __forceinline__ unsigned short f2bf(float x){
  unsigned int u = __float_as_uint(x);
  unsigned int r = (u + 0x7FFFu + ((u >> 16) & 1u)) >> 16;
  return (unsigned short)r;
}
__device__ __forceinline__ float bf2f(unsigned short h){
  return __uint_as_float(((unsigned int)h) << 16);
}

// Wigner small-d, quantum norm, CS phase. double precision.
__device__ double wigner_d_dev(int l, int mp, int m, double beta, const double* LF){
  double c = cos(0.5*beta), s = sin(0.5*beta);
  double pref = 0.5*(LF[l+mp] + LF[l-mp] + LF[l+m] + LF[l-m]);
  int lo = max(0, m-mp), hi = min(l+m, l-mp);
  double v = 0.0;
  for (int k = lo; k <= hi; ++k){
    double lg = pref - (LF[l+m-k] + LF[k] + LF[mp-m+k] + LF[l-mp-k]);
    double t = exp(lg) * pow(c, (double)(2*l + m - mp - 2*k)) * pow(s, (double)(mp - m + 2*k));
    v += ((mp - m + k) & 1) ? -t : t;
  }
  return v;
}

// ---- constants ----
__global__ void k0_consts(double* LF, double* wq){
  int t = threadIdx.x;
  if (t == 0){
    LF[0] = 0.0;
    double acc = 0.0;
    for (int i = 1; i < 70; ++i){ acc += log((double)i); LF[i] = acc; }
  }
  if (t < NJ){
    double b = 32.0;  // B_IN
    double sum = 0.0;
    for (int k = 0; k < 32; ++k)
      sum += sin((2.0*t+1.0)*(2.0*k+1.0)*M_PI/(4.0*b)) / (2.0*k+1.0);
    double a = (2.0/b) * sin(M_PI*(2.0*t+1.0)/(4.0*b)) * sum;
    wq[t] = a * M_PI / b;
  }
}

// wig[s][j] = w(beta_j) * d^l_{m,0}(beta_j)
__global__ void k1a_wig(const double* LF, const double* wq, float* wig){
  int s = blockIdx.x, j = threadIdx.x;
  int l, m; lm_from_s(s, l, m);
  double beta = (j + 0.5) * M_PI / (double)NJ;
  wig[s*NJ + j] = (float)(wq[j] * wigner_d_dev(l, m, 0, beta, LF));
}

// Fc[s][a] = conj(F[a][s])
__global__ void k1b_fc(const double* LF, float2* Fc){
  int gid = blockIdx.x * blockDim.x + threadIdx.x;
  if (gid >= 256 * NGRID) return;
  int s = gid / NGRID, a = gid % NGRID;
  int l, m; lm_from_s(s, l, m);
  int bidx = a / 8, aidx = a % 8;
  double beta  = (bidx + 1) * (M_PI / 8.0) / 3.0;
  double alpha = aidx * (M_PI / 4.0);
  double d  = wigner_d_dev(l, m, 0, beta, LF);
  double sq = sqrt((2.0*l + 1.0) / (4.0 * M_PI));
  Fc[s*NGRID + a] = make_float2((float)(sq*d*cos(m*alpha)), (float)(sq*d*sin(m*alpha)));
}

// Dt[idx][j] = (2l+1) * d^l_{m,n}(beta_out_j), idx = hoff(l)+m*(2l+1)+n+l, m>=0
__global__ void k1c_Dt(const double* LF, float* Dt){
  int gid = blockIdx.x * blockDim.x + threadIdx.x;
  if (gid >= NHALF * 32) return;
  int idx = gid >> 5, j = gid & 31;
  int l = 0;
  while (hoff(l+1) <= idx) l++;
  int t = idx - hoff(l), nm = 2*l + 1;
  int m = t / nm, n = t % nm - l;
  double beta = (j + 0.5) * M_PI / (double)NOUTD;
  Dt[gid] = (float)((2*l + 1) * wigner_d_dev(l, m, n, beta, LF));
}

// E fragments (lane-packed) + A2 fragments for MFMA phases of k6.
// Epack layout: [((gt*2+mat)*2+part)*512 + lane*8 + e], mat: 0=cos 1=sin, part: 0=hi 1=lo
// A2pack layout: [(at*2+part)*512 + lane*8 + e]
__global__ void k1f_pack(short* Epack, short* A2pack){
  int gid = blockIdx.x * blockDim.x + threadIdx.x;
  if (gid < 2048){
    int e = gid & 7, lane = (gid >> 3) & 63, mat = (gid >> 9) & 1, gt = (gid >> 10) & 1;
    int nn = (lane >> 4)*8 + e, g = gt*16 + (lane & 15);
    double v = 0.0;
    if (nn <= 30){
      double ang = 2.0 * M_PI * (double)((nn - 15) * g) / 32.0;
      v = mat ? sin(ang) : cos(ang);
    }
    unsigned short h = f2bf((float)v);
    float lo = (float)v - bf2f(h);
    Epack[((gt*2 + mat)*2 + 0)*512 + lane*8 + e] = (short)h;
    Epack[((gt*2 + mat)*2 + 1)*512 + lane*8 + e] = (short)f2bf(lo);
  } else if (gid < 3072){
    int g2 = gid - 2048;
    int e = g2 & 7, lane = (g2 >> 3) & 63, at = (g2 >> 9) & 1;
    int k = (lane >> 4)*8 + e, a = at*16 + (lane & 15);
    int m = k & 15;
    double s = (m == 0) ? 1.0 : 2.0;
    double ang = 2.0 * M_PI * (double)(m * a) / 32.0;
    double v = (k < 16) ? s * cos(ang) : -s * sin(ang);
    unsigned short h = f2bf((float)v);
    float lo = (float)v - bf2f(h);
    A2pack[(at*2 + 0)*512 + lane*8 + e] = (short)h;
    A2pack[(at*2 + 1)*512 + lane*8 + e] = (short)f2bf(lo);
  }
}

// kt[o][a][i] = kern[i][o][a]
__global__ __launch_bounds__(256) void k1e_kt(const float* __restrict__ kern, float* __restrict__ kt){
  int o = blockIdx.x;
  for (int t = threadIdx.x; t < NGRID*64; t += 256){
    int a = t >> 6, i = t & 63;
    kt[(o*NGRID + a)*64 + i] = kern[(i*64 + o)*NGRID + a];
  }
}

// ---- xfreq[mu][j][b][i] = sum_a x[b,i,j,a] e^{-2pi i a mu/64}, mu=0..15 ----
__global__ __launch_bounds__(256) void k2_xfreq(const float* __restrict__ x, float2* __restrict__ xf){
  __shared__ float xt[64*65];
  __shared__ float2 tw[64];
  int bid = blockIdx.x;
  int b = bid >> 6, i = bid & 63;
  const float* xp = x + (size_t)(b*64 + i) * 4096;
  for (int t = threadIdx.x; t < 4096; t += 256) xt[(t >> 6)*65 + (t & 63)] = xp[t];
  if (threadIdx.x < 64){
    float sv, cv;
    sincosf(-2.0f * (float)M_PI * threadIdx.x / 64.0f, &sv, &cv);
    tw[threadIdx.x] = make_float2(cv, sv);
  }
  __syncthreads();
  for (int t = threadIdx.x; t < 1024; t += 256){
    int mu = t >> 6, j = t & 63;
    float2 acc = make_float2(0.f, 0.f);
    const float* row = xt + j*65;
    int idx = 0;
    #pragma unroll 16
    for (int a = 0; a < 64; ++a){
      float2 w = tw[idx];
      idx = (idx + mu) & 63;
      acc.x = fmaf(row[a], w.x, acc.x);
      acc.y = fmaf(row[a], w.y, acc.y);
    }
    xf[(size_t)((mu*64 + j)*16 + b)*64 + i] = acc;
  }
}

// ---- xhat[h][b][i] = sum_j wig[s][j] * xf(b,i,j,m), h = l(l+1)/2 + m ----
__global__ __launch_bounds__(64) void k3_xhat(const float2* __restrict__ xf, const float* __restrict__ wig,
                                              float2* __restrict__ xhat){
  int blk = blockIdx.x;
  int h = blk >> 4, b = blk & 15, i = threadIdx.x;
  int l = 0;
  while (h2off(l+1) <= h) l++;
  int m = h - h2off(l);
  int s = l*l + l + m;
  float2 acc = make_float2(0.f, 0.f);
  for (int j = 0; j < NJ; ++j){
    float w = wig[s*NJ + j];
    float2 v = xf[(size_t)((m*64 + j)*16 + b)*64 + i];
    acc.x = fmaf(w, v.x, acc.x);
    acc.y = fmaf(w, v.y, acc.y);
  }
  xhat[(size_t)(h*16 + b)*64 + i] = acc;
}

// ---- yhc[s][o][i] = sum_a kt[o][a][i] * Fc[s][a] ----
__global__ __launch_bounds__(256) void k4_yhc(const float* __restrict__ kt, const float2* __restrict__ Fc,
                                              float2* __restrict__ yhc){
  __shared__ float2 fc[NGRID];
  int s = blockIdx.x;
  if (threadIdx.x < NGRID) fc[threadIdx.x] = Fc[s*NGRID + threadIdx.x];
  __syncthreads();
  for (int p = threadIdx.x; p < FOUT*FIN; p += 256){
    int o = p >> 6, i = p & 63;
    float2 acc = make_float2(0.f, 0.f);
    for (int a = 0; a < NGRID; ++a){
      float k = kt[(o*NGRID + a)*64 + i];
      acc.x = fmaf(k, fc[a].x, acc.x);
      acc.y = fmaf(k, fc[a].y, acc.y);
    }
    yhc[(size_t)(s*FOUT + o)*FIN + i] = acc;
  }
}

// ---- Z[bloc][o][half-lmn] = sum_i xhat * yhc ----
__global__ __launch_bounds__(256) void k5_z(const float2* __restrict__ xhat, const float2* __restrict__ yhc,
                                            float2* __restrict__ Z, int b0){
  __shared__ float2 Xs[16*65];
  __shared__ float2 Ys[31*65];
  int bloc = blockIdx.x >> 6, o = blockIdx.x & 63;
  int b = b0 + bloc;
  float2* zout = Z + (size_t)(bloc*64 + o) * NHALF;
  int rt = threadIdx.x >> 4, ct = threadIdx.x & 15;
  for (int l = 0; l < 16; ++l){
    int rx = l + 1, ry = 2*l + 1;
    for (int t = threadIdx.x; t < rx*64; t += 256){
      int r = t >> 6, i = t & 63;
      Xs[r*65 + i] = xhat[(size_t)((h2off(l) + r)*16 + b)*64 + i];
    }
    for (int t = threadIdx.x; t < ry*64; t += 256){
      int r = t >> 6, i = t & 63;
      Ys[r*65 + i] = yhc[(size_t)((l*l + r)*FOUT + o)*FIN + i];
    }
    __syncthreads();
    int n0 = 2*ct;
    if ((rt <= l) && (n0 <= 2*l)){
      int n1 = min(n0 + 1, 2*l);
      float z0r = 0.f, z0i = 0.f, z1r = 0.f, z1i = 0.f;
      const float2* xr = Xs + rt*65;
      const float2* y0 = Ys + n0*65;
      const float2* y1 = Ys + n1*65;
      #pragma unroll 8
      for (int i = 0; i < 64; ++i){
        float2 xv = xr[i];
        float2 a0 = y0[i], a1 = y1[i];
        z0r += xv.x*a0.x - xv.y*a0.y;  z0i += xv.x*a0.y + xv.y*a0.x;
        z1r += xv.x*a1.x - xv.y*a1.y;  z1i += xv.x*a1.y + xv.y*a1.x;
      }
      int base = hoff(l) + rt*(2*l+1);
      zout[base + n0] = make_float2(z0r, z0i);
      if (n0 + 1 <= 2*l) zout[base + n0 + 1] = make_float2(z1r, z1i);
    }
    __syncthreads();
  }
}

// ---- k6: block=(bloc,o); 4 waves x 8 j. W-build (VALU) -> MFMA n-DFT -> MFMA a-DFT ----
__global__ __launch_bounds__(256) void k6_out(const float2* __restrict__ Z, const float* __restrict__ Dt,
                                              const short* __restrict__ Epack, const short* __restrict__ A2pack,
                                              const float* __restrict__ bias, float* __restrict__ out, int b0){
  __shared__ float2 Zl[NHALF];
  __shared__ __align__(16) short stag[4][2048];   // per-wave: hi[32][32] @0, lo[32][32] @1024 (shorts)
  int o = blockIdx.x & 63, bloc = blockIdx.x >> 6;
  int tid = threadIdx.x;
  const float2* zp = Z + (size_t)(bloc*64 + o) * NHALF;
  for (int t = tid; t < NHALF; t += 256) Zl[t] = zp[t];
  __syncthreads();

  int w = tid >> 6, lane = tid & 63;
  int q = lane >> 4, mrow = lane & 15;   // A-frag: row m = mrow, k = 8q+e ; C-frag: col = mrow, rows 4q+r
  float bo = bias[o];
  short* sw = stag[w];
  const short8* EP = (const short8*)Epack;
  const short8* AP = (const short8*)A2pack;
  size_t obase0 = (size_t)((b0 + bloc)*64 + o) * 32768;

  for (int round = 0; round < 2; ++round){
    int j0 = w*8 + round*4;
    float Wr[4][8], Wi[4][8];
    #pragma unroll
    for (int jj = 0; jj < 4; ++jj)
      #pragma unroll
      for (int e = 0; e < 8; ++e){ Wr[jj][e] = 0.f; Wi[jj][e] = 0.f; }

    // W-build: W[j][m][nn] = sum_l Z[l,m,n] * Dt[idx][j]
    #pragma unroll
    for (int e = 0; e < 8; ++e){
      int nn = q*8 + e;
      if (nn <= 30){
        int n = nn - 15;
        int na = n < 0 ? -n : n;
        int lmin = mrow > na ? mrow : na;
        int idx = hoff(lmin) + mrow*(2*lmin + 1) + n + lmin;
        for (int l = lmin; l < 16; ++l){
          float2 z = Zl[idx];
          f32x4 d4 = *(const f32x4*)&Dt[idx*32 + j0];
          #pragma unroll
          for (int jj = 0; jj < 4; ++jj){
            Wr[jj][e] = fmaf(z.x, d4[jj], Wr[jj][e]);
            Wi[jj][e] = fmaf(z.y, d4[jj], Wi[jj][e]);
          }
          idx += (l + 1)*(2*l + 1) + 2*mrow + 1;
        }
      }
    }

    #pragma unroll
    for (int jj = 0; jj < 4; ++jj){
      int j = j0 + jj;
      // convert W row to bf16 hi/lo A-fragments (already in A-frag lane layout)
      short8 wrh, wrl, wih, wil;
      #pragma unroll
      for (int e = 0; e < 8; ++e){
        unsigned short h1 = f2bf(Wr[jj][e]);
        wrh[e] = (short)h1; wrl[e] = (short)f2bf(Wr[jj][e] - bf2f(h1));
        unsigned short h2 = f2bf(Wi[jj][e]);
        wih[e] = (short)h2; wil[e] = (short)f2bf(Wi[jj][e] - bf2f(h2));
      }
      // phase 1: T[m][g] = sum_nn W[m][nn] e^{2pi i (nn-15) g/32}
      #pragma unroll
      for (int gt = 0; gt < 2; ++gt){
        short8 ech = EP[((gt*2 + 0)*2 + 0)*64 + lane];
        short8 ecl = EP[((gt*2 + 0)*2 + 1)*64 + lane];
        short8 esh = EP[((gt*2 + 1)*2 + 0)*64 + lane];
        short8 esl = EP[((gt*2 + 1)*2 + 1)*64 + lane];
        f32x4 ta = {0.f,0.f,0.f,0.f}, tb = {0.f,0.f,0.f,0.f}, ti = {0.f,0.f,0.f,0.f};
        ta = __builtin_amdgcn_mfma_f32_16x16x32_bf16(wrh, ech, ta, 0, 0, 0);
        ta = __builtin_amdgcn_mfma_f32_16x16x32_bf16(wrl, ech, ta, 0, 0, 0);
        ta = __builtin_amdgcn_mfma_f32_16x16x32_bf16(wrh, ecl, ta, 0, 0, 0);
        tb = __builtin_amdgcn_mfma_f32_16x16x32_bf16(wih, esh, tb, 0, 0, 0);
        tb = __builtin_amdgcn_mfma_f32_16x16x32_bf16(wil, esh, tb, 0, 0, 0);
        tb = __builtin_amdgcn_mfma_f32_16x16x32_bf16(wih, esl, tb, 0, 0, 0);
        ti = __builtin_amdgcn_mfma_f32_16x16x32_bf16(wrh, esh, ti, 0, 0, 0);
        ti = __builtin_amdgcn_mfma_f32_16x16x32_bf16(wrl, esh, ti, 0, 0, 0);
        ti = __builtin_amdgcn_mfma_f32_16x16x32_bf16(wrh, esl, ti, 0, 0, 0);
        ti = __builtin_amdgcn_mfma_f32_16x16x32_bf16(wih, ech, ti, 0, 0, 0);
        ti = __builtin_amdgcn_mfma_f32_16x16x32_bf16(wil, ech, ti, 0, 0, 0);
        ti = __builtin_amdgcn_mfma_f32_16x16x32_bf16(wih, ecl, ti, 0, 0, 0);
        // stage stacked B2 = [Tr(k=m) ; Ti(k=16+m)] as bf16 hi/lo, row = 16*gt+col
        int row = (16*gt + mrow) * 32;
        short4 pk0, pk1;
        {
          float t0 = ta[0] - tb[0], t1 = ta[1] - tb[1], t2 = ta[2] - tb[2], t3 = ta[3] - tb[3];
          unsigned short h0 = f2bf(t0), h1 = f2bf(t1), h2 = f2bf(t2), h3 = f2bf(t3);
          pk0.x = (short)h0; pk0.y = (short)h1; pk0.z = (short)h2; pk0.w = (short)h3;
          pk1.x = (short)f2bf(t0 - bf2f(h0)); pk1.y = (short)f2bf(t1 - bf2f(h1));
          pk1.z = (short)f2bf(t2 - bf2f(h2)); pk1.w = (short)f2bf(t3 - bf2f(h3));
        }
        *(short4*)&sw[row + 4*q]        = pk0;
        *(short4*)&sw[1024 + row + 4*q] = pk1;
        {
          float t0 = ti[0], t1 = ti[1], t2 = ti[2], t3 = ti[3];
          unsigned short h0 = f2bf(t0), h1 = f2bf(t1), h2 = f2bf(t2), h3 = f2bf(t3);
          pk0.x = (short)h0; pk0.y = (short)h1; pk0.z = (short)h2; pk0.w = (short)h3;
          pk1.x = (short)f2bf(t0 - bf2f(h0)); pk1.y = (short)f2bf(t1 - bf2f(h1));
          pk1.z = (short)f2bf(t2 - bf2f(h2)); pk1.w = (short)f2bf(t3 - bf2f(h3));
        }
        *(short4*)&sw[row + 16 + 4*q]        = pk0;
        *(short4*)&sw[1024 + row + 16 + 4*q] = pk1;
      }
      // phase 2: out[a][g] = A2 . [Tr;Ti]
      float* op = out + obase0 + (size_t)j * 1024;
      #pragma unroll
      for (int at = 0; at < 2; ++at){
        short8 a2h = AP[(at*2 + 0)*64 + lane];
        short8 a2l = AP[(at*2 + 1)*64 + lane];
        #pragma unroll
        for (int gt = 0; gt < 2; ++gt){
          short8 bh = *(const short8*)&sw[(16*gt + mrow)*32 + 8*q];
          short8 bl = *(const short8*)&sw[1024 + (16*gt + mrow)*32 + 8*q];
          f32x4 acc = {0.f,0.f,0.f,0.f};
          acc = __builtin_amdgcn_mfma_f32_16x16x32_bf16(a2h, bh, acc, 0, 0, 0);
          acc = __builtin_amdgcn_mfma_f32_16x16x32_bf16(a2l, bh, acc, 0, 0, 0);
          acc = __builtin_amdgcn_mfma_f32_16x16x32_bf16(a2h, bl, acc, 0, 0, 0);
          #pragma unroll
          for (int r = 0; r < 4; ++r)
            op[(16*at + 4*q + r)*32 + 16*gt + mrow] = acc[r] + bo;
        }
      }
    }
  }
}

extern "C" void kernel_launch(void* const* d_in, const int* in_sizes, int n_in,
                              void* d_out, int out_size, void* d_ws, size_t ws_size,
                              hipStream_t stream){
  const float* x    = (const float*)d_in[0];
  const float* kern = (const float*)d_in[1];
  const float* bias = (const float*)d_in[2];
  float* out = (float*)d_out;

  char* ws = (char*)d_ws;
  size_t off = 0;
  auto alloc = [&](size_t bytes) -> char* {
    char* p = ws + off;
    off = (off + bytes + 511) & ~(size_t)511;
    return p;
  };
  double* LF   = (double*)alloc(70 * 8);
  double* wq   = (double*)alloc(64 * 8);
  float*  wig  = (float* )alloc((size_t)256 * NJ * 4);
  float2* Fc   = (float2*)alloc((size_t)256 * NGRID * 8);
  float*  Dt   = (float* )alloc((size_t)NHALF * 32 * 4);
  short*  Ep   = (short* )alloc(4096 * 2);
  short*  A2p  = (short* )alloc(2048 * 2);
  float*  kt   = (float* )alloc((size_t)FOUT * NGRID * 64 * 4);
  float2* xf   = (float2*)alloc((size_t)16 * 64 * 16 * 64 * 8);
  float2* xhat = (float2*)alloc((size_t)NH2 * NB * FIN * 8);
  float2* yhc  = (float2*)alloc((size_t)256 * FOUT * FIN * 8);
  size_t fixed = off;

  size_t zbytes_per_b = (size_t)FOUT * NHALF * 8;
  int chunk = NB;
  while (chunk > 1 && fixed + (size_t)chunk * zbytes_per_b > ws_size) chunk >>= 1;
  float2* Z = (float2*)alloc((size_t)chunk * zbytes_per_b);

  hipLaunchKernelGGL(k0_consts, dim3(1), dim3(256), 0, stream, LF, wq);
  hipLaunchKernelGGL(k1a_wig,  dim3(256), dim3(NJ), 0, stream, LF, wq, wig);
  hipLaunchKernelGGL(k1b_fc,   dim3((256*NGRID + 255)/256), dim3(256), 0, stream, LF, Fc);
  hipLaunchKernelGGL(k1c_Dt,   dim3((NHALF*32 + 255)/256), dim3(256), 0, stream, LF, Dt);
  hipLaunchKernelGGL(k1f_pack, dim3(12), dim3(256), 0, stream, Ep, A2p);
  hipLaunchKernelGGL(k1e_kt,   dim3(FOUT), dim3(256), 0, stream, kern, kt);
  hipLaunchKernelGGL(k2_xfreq, dim3(NB*FIN), dim3(256), 0, stream, x, xf);
  hipLaunchKernelGGL(k3_xhat,  dim3(NH2*NB), dim3(64), 0, stream, xf, wig, xhat);
  hipLaunchKernelGGL(k4_yhc,   dim3(256), dim3(256), 0, stream, kt, Fc, yhc);

  for (int b0 = 0; b0 < NB; b0 += chunk){
    hipLaunchKernelGGL(k5_z,   dim3(chunk*FOUT), dim3(256), 0, stream, xhat, yhc, Z, b0);
    hipLaunchKernelGGL(k6_out, dim3(chunk*FOUT), dim3(256), 0, stream, Z, Dt, Ep, A2p, bias, out, b0);
  }
}